// Round 8
// baseline (15609.773 us; speedup 1.0000x reference)
//
#include <hip/hip_runtime.h>

#define NN 64
#define LD 65            // odd stride: 65 % 32 == 1 -> lane-vs-row access is 2-way (free).
                         // LD=66 measured 6.9x bank conflicts (4-way) -> keep 65.
#define NPAIR 32
#define BLOCK 256
#define MAXSWEEP 11
#define EPSF 1e-6f
#define TRI 2080
#define BATCH 4096
#define MU_OFF 16777216
#define LV_OFF 16908288
#define RELTOL_MAIN 1e-8f
#define RELTOL_PREP 1e-12f
#define RELTOL_VALS 1e-8f

__device__ __forceinline__ int triOff(int i) { return (i * (129 - i)) >> 1; }

__device__ __forceinline__ float bn_leaky(float h, float g, float bb) {
  h = (h >= 0.0f) ? h : 0.2f * h;
  return h * (1.0f / sqrtf(1.0f + 1e-5f)) * g + bb;
}

// Parallel cyclic Jacobi eigensolver, 64x64 symmetric in LDS (ld 65).
// XOR 1-factorization: round m = 1..63 pairs i with i^m (valid cyclic ordering).
// Pair rep p has top-bit-of-m clear; q = p^m. Two-phase update with lane=column:
//   row phase  A[p*LD+j] / A[q*LD+j]  -> fixed row, consecutive lanes: conflict-free
//   col phase  A[j*LD+p] / A[j*LD+q]  -> banks (j+p)%32: exact 2-way (free at LD=65)
// (replaces the 2x2-block one-phase scheme whose scattered rep-rep addressing
//  measured 1.74e9 bank-conflict cycles, 15.6x baseline)
// Angles computed IN-WAVE (all lanes redundantly, pair 8w+(j&7); 3 same-address
// broadcast reads, then __shfl) -- safe: a wave's angle reads touch only rows it
// alone writes in the row phase. 2 barriers/round. off^2 convergence accumulated
// FREE from the last round's col-phase writes (cols partition the matrix).
// On exit: diag(A) = eigenvalues (unsorted), V = eigenvectors (cols), if WITH_V.
template<bool WITH_V>
__device__ void jacobi64(float* A, float* V, float* red, float relTol)
{
  const int tid = threadIdx.x;
  const int w   = tid >> 6;   // wave id 0..3
  const int j   = tid & 63;   // lane

  if (WITH_V) {
    for (int idx = tid; idx < NN * LD; idx += BLOCK) V[idx] = 0.0f;
    __syncthreads();
    if (tid < NN) V[tid * LD + tid] = 1.0f;
  }

  // Frobenius^2 (rotation invariant) -> tolerance
  float fp = 0.0f;
  for (int idx = tid; idx < NN * NN; idx += BLOCK) {
    float a = A[(idx >> 6) * LD + (idx & 63)];
    fp += a * a;
  }
  #pragma unroll
  for (int o = 32; o > 0; o >>= 1) fp += __shfl_xor(fp, o);
  if (j == 0) red[w] = fp;
  __syncthreads();          // also makes V diag writes visible
  const float tol = (red[0] + red[1] + red[2] + red[3]) * relTol + 1e-30f;

  for (int sweep = 0; sweep < MAXSWEEP; ++sweep) {
    for (int m = 1; m < 64; ++m) {
      const int b  = 31 - __clz(m);          // wave-uniform
      const int lm = (1 << b) - 1;

      // --- in-wave angles: every lane computes pair kk = 8w + (j&7) ---
      // (8-way same-address reads = LDS broadcast, free; no extra barrier:
      //  these rows are written only by THIS wave's row phase, after the reads)
      const int kk = (w << 3) + (j & 7);
      const int pk = ((kk >> b) << (b + 1)) | (kk & lm);   // bit b clear
      const int qk = pk ^ m;
      float app = A[pk * LD + pk];
      float aqq = A[qk * LD + qk];
      float apq = A[pk * LD + qk];
      float cv = 1.0f, sv = 0.0f;
      if (fabsf(apq) > 1e-36f) {
        float th = (aqq - app) / (2.0f * apq);
        float t  = 1.0f / (fabsf(th) + sqrtf(th * th + 1.0f));
        if (th < 0.0f) t = -t;
        cv = 1.0f / sqrtf(t * t + 1.0f);
        sv = t * cv;
      }

      float cc[8], ss[8]; int pp[8], qq[8];
      #pragma unroll
      for (int it = 0; it < 8; ++it) {
        cc[it] = __shfl(cv, it);             // lane it computed pair 8w+it
        ss[it] = __shfl(sv, it);
        const int k2 = (w << 3) + it;
        pp[it] = ((k2 >> b) << (b + 1)) | (k2 & lm);
        qq[it] = pp[it] ^ m;
      }

      // --- row phase: rows of our 8 pairs, col = j (batched, unconditional) ---
      float ap[8], aq[8];
      #pragma unroll
      for (int it = 0; it < 8; ++it) {
        ap[it] = A[pp[it] * LD + j];
        aq[it] = A[qq[it] * LD + j];
      }
      #pragma unroll
      for (int it = 0; it < 8; ++it) {
        A[pp[it] * LD + j] = cc[it] * ap[it] - ss[it] * aq[it];
        A[qq[it] * LD + j] = ss[it] * ap[it] + cc[it] * aq[it];
      }
      __syncthreads();

      // --- col phase (+ V), same 8 pairs, row = j ---
      float lo = 0.0f;
      #pragma unroll
      for (int it = 0; it < 8; ++it) {
        ap[it] = A[j * LD + pp[it]];
        aq[it] = A[j * LD + qq[it]];
      }
      #pragma unroll
      for (int it = 0; it < 8; ++it) {
        float np = cc[it] * ap[it] - ss[it] * aq[it];
        float nq = ss[it] * ap[it] + cc[it] * aq[it];
        A[j * LD + pp[it]] = np;
        A[j * LD + qq[it]] = nq;
        if (m == 63) {                       // free off^2 on the sweep's last round
          if (j != pp[it]) lo += np * np;
          if (j != qq[it]) lo += nq * nq;
        }
      }
      if (WITH_V) {
        float vp[8], vq[8];
        #pragma unroll
        for (int it = 0; it < 8; ++it) {
          vp[it] = V[j * LD + pp[it]];
          vq[it] = V[j * LD + qq[it]];
        }
        #pragma unroll
        for (int it = 0; it < 8; ++it) {
          V[j * LD + pp[it]] = cc[it] * vp[it] - ss[it] * vq[it];
          V[j * LD + qq[it]] = ss[it] * vp[it] + cc[it] * vq[it];
        }
      }
      if (m == 63) {
        #pragma unroll
        for (int o = 32; o > 0; o >>= 1) lo += __shfl_xor(lo, o);
        if (j == 0) red[w] = lo;
      }
      __syncthreads();
    }
    const float off2 = red[0] + red[1] + red[2] + red[3];
    if (off2 <= tol) break;     // uniform
  }
  __syncthreads();
}

// O = Lg @ S ; Lg global row-major 64 (wave-uniform scalar loads), S LDS (ld 65).
__device__ void gemm_gS(const float* __restrict__ Lg, const float* S, float* O)
{
  const int tid = threadIdx.x;
  const int j  = tid & 63;
  const int iw = __builtin_amdgcn_readfirstlane((tid >> 6) << 4);
  float acc[16];
  #pragma unroll
  for (int ii = 0; ii < 16; ++ii) acc[ii] = 0.0f;
  for (int kb = 0; kb < 64; kb += 4) {
    float sv0 = S[(kb + 0) * LD + j];
    float sv1 = S[(kb + 1) * LD + j];
    float sv2 = S[(kb + 2) * LD + j];
    float sv3 = S[(kb + 3) * LD + j];
    #pragma unroll
    for (int ii = 0; ii < 16; ++ii) {
      const float* lr = Lg + (iw + ii) * 64 + kb;   // wave-uniform -> s_load
      acc[ii] += lr[0] * sv0 + lr[1] * sv1 + lr[2] * sv2 + lr[3] * sv3;
    }
  }
  #pragma unroll
  for (int ii = 0; ii < 16; ++ii) O[(iw + ii) * LD + j] = acc[ii];
}

// O = S @ Rg with Rg SYMMETRIC global (rows, wave-uniform scalar):
// O[i][j] = sum_k S[i][k]*Rg[j*64+k]
__device__ void gemm_SgT(const float* S, const float* __restrict__ Rg, float* O)
{
  const int tid = threadIdx.x;
  const int i  = tid & 63;
  const int jw = __builtin_amdgcn_readfirstlane((tid >> 6) << 4);
  float acc[16];
  #pragma unroll
  for (int jj = 0; jj < 16; ++jj) acc[jj] = 0.0f;
  for (int kb = 0; kb < 64; kb += 4) {
    float s0 = S[i * LD + kb + 0];
    float s1 = S[i * LD + kb + 1];
    float s2 = S[i * LD + kb + 2];
    float s3 = S[i * LD + kb + 3];
    #pragma unroll
    for (int jj = 0; jj < 16; ++jj) {
      const float* rr = Rg + (jw + jj) * 64 + kb;   // wave-uniform -> s_load
      acc[jj] += s0 * rr[0] + s1 * rr[1] + s2 * rr[2] + s3 * rr[3];
    }
  }
  #pragma unroll
  for (int jj = 0; jj < 16; ++jj) O[i * LD + jw + jj] = acc[jj];
}

// O[i][j] = sum_k P[i][k] * w[k] * V[j][k]  (all LDS). O may alias V or P.
__device__ void gemm_ADT(const float* P, const float* w, const float* V, float* O)
{
  const int tid = threadIdx.x;
  const int i  = tid & 63;
  const int jw = __builtin_amdgcn_readfirstlane((tid >> 6) << 4);
  float acc[16];
  #pragma unroll
  for (int jj = 0; jj < 16; ++jj) acc[jj] = 0.0f;
  for (int k = 0; k < 64; ++k) {
    float pw = P[i * LD + k] * w[k];
    #pragma unroll
    for (int jj = 0; jj < 16; ++jj) acc[jj] += pw * V[(jw + jj) * LD + k];
  }
  __syncthreads();
  #pragma unroll
  for (int jj = 0; jj < 16; ++jj) O[i * LD + jw + jj] = acc[jj];
}

// --- prep: eigh(ref + eps I) -> rm = ref^{-1/2}, rp = ref^{1/2} into ws ---
__global__ __launch_bounds__(BLOCK) void vae_prep(const float* __restrict__ ref,
                                                  float* __restrict__ rmrp)
{
  __shared__ __align__(16) float sA[NN * LD];
  __shared__ __align__(16) float sT[NN * LD];
  __shared__ float red[BLOCK];
  __shared__ float wb[64];
  const int tid = threadIdx.x;

  for (int idx = tid; idx < NN * NN; idx += BLOCK) {
    int i = idx >> 6, j = idx & 63;
    sA[i * LD + j] = ref[idx] + ((i == j) ? EPSF : 0.0f);
  }
  __syncthreads();
  jacobi64<true>(sA, sT, red, RELTOL_PREP);
  if (tid < 64) wb[tid] = sA[tid * LD + tid];
  __syncthreads();

  const int i  = tid & 63;
  const int jw = (tid >> 6) << 4;
  float am[16], aps[16];
  #pragma unroll
  for (int jj = 0; jj < 16; ++jj) { am[jj] = 0.0f; aps[jj] = 0.0f; }
  for (int k = 0; k < 64; ++k) {
    float vik = sT[i * LD + k];
    float wk  = wb[k];
    float rs  = 1.0f / sqrtf(wk);   // ref SPD: wk >= ~0.5
    float sq  = sqrtf(wk);
    float pr = vik * rs, pq = vik * sq;
    #pragma unroll
    for (int jj = 0; jj < 16; ++jj) {
      float vjk = sT[(jw + jj) * LD + k];
      am[jj]  += pr * vjk;
      aps[jj] += pq * vjk;
    }
  }
  #pragma unroll
  for (int jj = 0; jj < 16; ++jj) {
    rmrp[i * 64 + jw + jj]        = am[jj];
    rmrp[4096 + i * 64 + jw + jj] = aps[jj];
  }
}

// --- main: one block per batch item, fully fused ---
__global__ __launch_bounds__(BLOCK) void vae_main(
    const float* __restrict__ x,   const float* __restrict__ ref,
    const float* __restrict__ rmrp,
    const float* __restrict__ w1,  const float* __restrict__ b1,
    const float* __restrict__ g1,  const float* __restrict__ bb1,
    const float* __restrict__ w2,  const float* __restrict__ b2,
    const float* __restrict__ g2,  const float* __restrict__ bb2,
    const float* __restrict__ muw, const float* __restrict__ mub,
    const float* __restrict__ lvw, const float* __restrict__ lvb,
    const float* __restrict__ dw1, const float* __restrict__ db1,
    const float* __restrict__ dg1, const float* __restrict__ dbb1,
    const float* __restrict__ dw2, const float* __restrict__ db2,
    const float* __restrict__ dg2, const float* __restrict__ dbb2,
    const float* __restrict__ dw3, const float* __restrict__ db3,
    float* __restrict__ out)
{
  __shared__ __align__(16) float sA[NN * LD];
  __shared__ __align__(16) float sT[NN * LD];   // also hosts svec (2080 <= 4160)
  __shared__ float red[BLOCK];
  __shared__ float h1s[128], h2s[64], zs[32], d1s[64], d2s[128];
  __shared__ float wb[64];
  __shared__ float shiftv;

  const int tid = threadIdx.x;
  const int b   = blockIdx.x;
  const float* rm = rmrp;
  const float* rp = rmrp + 4096;
  float* svec = sT;   // alias: sT is dead during the MLP phase

  // load x (shift for _ensure_spd(x) is provably 0: lambda_min(x) >= 0.5)
  for (int idx = tid; idx < 4096; idx += BLOCK)
    sA[(idx >> 6) * LD + (idx & 63)] = x[b * 4096 + idx];
  __syncthreads();

  gemm_gS(rm, sA, sT);            // T = rm @ x
  __syncthreads();
  gemm_SgT(sT, rm, sA);           // A = T @ rm = s
  __syncthreads();

  jacobi64<true>(sA, sT, red, RELTOL_MAIN);  // s = V w V^T (V in sT)
  if (tid < 64) wb[tid] = logf(fmaxf(sA[tid * LD + tid], 1e-12f));
  __syncthreads();

  gemm_gS(rm, sT, sA);            // A = rm @ V
  __syncthreads();
  gemm_ADT(sA, wb, sT, sT);       // T = (rm V) diag(log w) V^T  (alias-safe)
  __syncthreads();
  gemm_SgT(sT, rp, sA);           // A = tang = T @ rp
  __syncthreads();

  // vec = upper-triangle of tang (row-major triu order) -> svec (in sT)
  for (int idx = tid; idx < TRI; idx += BLOCK) {
    int i = (int)((129.0f - sqrtf(16641.0f - 8.0f * (float)idx)) * 0.5f);
    while (triOff(i + 1) <= idx) ++i;
    while (triOff(i) > idx) --i;
    int jj = i + (idx - triOff(i));
    svec[idx] = sA[i * LD + jj];
  }
  __syncthreads();

  // encoder L1: 2080 -> 128
  {
    int o = tid & 127, half = tid >> 7;
    const float4* wr = (const float4*)(w1 + o * 2080 + half * 1040);
    const float4* vv = (const float4*)(svec + half * 1040);
    float acc = 0.0f;
    for (int i4 = 0; i4 < 260; ++i4) {
      float4 a = wr[i4], v4 = vv[i4];
      acc += a.x * v4.x + a.y * v4.y + a.z * v4.z + a.w * v4.w;
    }
    red[tid] = acc;
    __syncthreads();
    if (tid < 128)
      h1s[tid] = bn_leaky(red[tid] + red[tid + 128] + b1[tid], g1[tid], bb1[tid]);
    __syncthreads();
  }
  // encoder L2: 128 -> 64
  {
    int o = tid & 63, half = tid >> 6;
    const float* wr = w2 + o * 128 + half * 32;
    const float* hh = h1s + half * 32;
    float acc = 0.0f;
    #pragma unroll 8
    for (int i = 0; i < 32; ++i) acc += wr[i] * hh[i];
    red[tid] = acc;
    __syncthreads();
    if (tid < 64)
      h2s[tid] = bn_leaky(red[tid] + red[tid + 64] + red[tid + 128] + red[tid + 192] + b2[tid],
                          g2[tid], bb2[tid]);
    __syncthreads();
  }
  // mu / logvar: 64 -> 32 each (z = mu)
  if (tid < 64) {
    int o = tid & 31;
    const float* wr = (tid < 32 ? muw : lvw) + o * 64;
    float acc = (tid < 32 ? mub : lvb)[o];
    for (int i = 0; i < 64; ++i) acc += wr[i] * h2s[i];
    if (tid < 32) { zs[o] = acc; out[MU_OFF + b * 32 + o] = acc; }
    else          { out[LV_OFF + b * 32 + o] = acc; }
  }
  __syncthreads();
  // decoder L1: 32 -> 64
  if (tid < 64) {
    const float* wr = dw1 + tid * 32;
    float acc = db1[tid];
    for (int i = 0; i < 32; ++i) acc += wr[i] * zs[i];
    d1s[tid] = bn_leaky(acc, dg1[tid], dbb1[tid]);
  }
  __syncthreads();
  // decoder L2: 64 -> 128
  if (tid < 128) {
    const float* wr = dw2 + tid * 64;
    float acc = db2[tid];
    for (int i = 0; i < 64; ++i) acc += wr[i] * d1s[i];
    d2s[tid] = bn_leaky(acc, dg2[tid], dbb2[tid]);
  }
  __syncthreads();
  // decoder L3: 128 -> 2080 (vdec into svec)
  for (int o = tid; o < TRI; o += BLOCK) {
    const float4* wr = (const float4*)(dw3 + o * 128);
    float acc = db3[o];
    #pragma unroll 8
    for (int k4 = 0; k4 < 32; ++k4) {
      float4 a = wr[k4];
      acc += a.x * d2s[k4 * 4] + a.y * d2s[k4 * 4 + 1] + a.z * d2s[k4 * 4 + 2] + a.w * d2s[k4 * 4 + 3];
    }
    svec[o] = acc;
  }
  __syncthreads();

  // mtil = symmetric(vdec) + eps I  -> sA
  for (int idx = tid; idx < 4096; idx += BLOCK) {
    int i = idx >> 6, jj = idx & 63;
    int lo = (i < jj) ? i : jj, hi = (i < jj) ? jj : i;
    sA[i * LD + jj] = svec[triOff(lo) + (hi - lo)] + ((i == jj) ? EPSF : 0.0f);
  }
  __syncthreads();

  // ===== exp(mtil) via scaling & squaring (replaces 2nd Jacobi eigh) =====
  {
    const int ti = tid >> 4;          // 0..15 (row tile)
    const int tj = tid & 15;          // 0..15 (col tile)
    const int r0 = ti << 2, c0 = tj << 2;

    // inf-norm (symmetric => bounds spectral norm)
    if (tid < 64) {
      float rs = 0.0f;
      for (int jj2 = 0; jj2 < 64; ++jj2) rs += fabsf(sA[tid * LD + jj2]);
      red[tid] = rs;
    }
    __syncthreads();
    if (tid < 32) red[tid] = fmaxf(red[tid], red[tid + 32]);
    __syncthreads();
    if (tid < 16) red[tid] = fmaxf(red[tid], red[tid + 16]);
    __syncthreads();
    if (tid < 8)  red[tid] = fmaxf(red[tid], red[tid + 8]);
    __syncthreads();
    if (tid < 4)  red[tid] = fmaxf(fmaxf(red[tid], red[tid + 4]),
                                   fmaxf(red[tid + 2] , red[(tid + 2) & 3]));
    __syncthreads();
    float R = fmaxf(fmaxf(red[0], red[1]), fmaxf(red[2], red[3]));

    int kpow = 0;
    float t = R;
    while (t > 0.25f && kpow < 24) { t *= 0.5f; ++kpow; }
    const float sc = ldexpf(1.0f, -kpow);

    // X = mtil * 2^-k (in place, sA)
    for (int idx = tid; idx < 4096; idx += BLOCK) {
      int i = idx >> 6, jj = idx & 63;
      sA[i * LD + jj] *= sc;
    }
    __syncthreads();

    // E = I + X + sum_{d=2..8} X^d/d!   (E in registers, powers ping in sT)
    float E[16];
    #pragma unroll
    for (int rr = 0; rr < 4; ++rr)
      #pragma unroll
      for (int c = 0; c < 4; ++c)
        E[rr * 4 + c] = ((r0 + rr) == (c0 + c) ? 1.0f : 0.0f) + sA[(r0 + rr) * LD + c0 + c];

    const float coef[7] = { 0.5f, 0.16666667f, 0.041666668f, 0.008333334f,
                            0.0013888889f, 1.9841270e-4f, 2.4801587e-5f };

    // d = 2: P = X*X  (reads sA only; sT dead after svec consumed)
    {
      float acc[16];
      #pragma unroll
      for (int u = 0; u < 16; ++u) acc[u] = 0.0f;
      for (int kk = 0; kk < 64; ++kk) {
        float a0 = sA[(r0 + 0) * LD + kk], a1 = sA[(r0 + 1) * LD + kk];
        float a2 = sA[(r0 + 2) * LD + kk], a3 = sA[(r0 + 3) * LD + kk];
        float b0 = sA[kk * LD + c0 + 0], b1v = sA[kk * LD + c0 + 1];
        float b2v = sA[kk * LD + c0 + 2], b3 = sA[kk * LD + c0 + 3];
        acc[0] += a0 * b0;  acc[1] += a0 * b1v;  acc[2] += a0 * b2v;  acc[3] += a0 * b3;
        acc[4] += a1 * b0;  acc[5] += a1 * b1v;  acc[6] += a1 * b2v;  acc[7] += a1 * b3;
        acc[8] += a2 * b0;  acc[9] += a2 * b1v;  acc[10] += a2 * b2v; acc[11] += a2 * b3;
        acc[12] += a3 * b0; acc[13] += a3 * b1v; acc[14] += a3 * b2v; acc[15] += a3 * b3;
      }
      __syncthreads();
      #pragma unroll
      for (int rr = 0; rr < 4; ++rr)
        #pragma unroll
        for (int c = 0; c < 4; ++c) {
          sT[(r0 + rr) * LD + c0 + c] = acc[rr * 4 + c];
          E[rr * 4 + c] += coef[0] * acc[rr * 4 + c];
        }
      __syncthreads();
    }
    // d = 3..8: P = P*X (in place via register staging)
    for (int d = 3; d <= 8; ++d) {
      float acc[16];
      #pragma unroll
      for (int u = 0; u < 16; ++u) acc[u] = 0.0f;
      for (int kk = 0; kk < 64; ++kk) {
        float a0 = sT[(r0 + 0) * LD + kk], a1 = sT[(r0 + 1) * LD + kk];
        float a2 = sT[(r0 + 2) * LD + kk], a3 = sT[(r0 + 3) * LD + kk];
        float b0 = sA[kk * LD + c0 + 0], b1v = sA[kk * LD + c0 + 1];
        float b2v = sA[kk * LD + c0 + 2], b3 = sA[kk * LD + c0 + 3];
        acc[0] += a0 * b0;  acc[1] += a0 * b1v;  acc[2] += a0 * b2v;  acc[3] += a0 * b3;
        acc[4] += a1 * b0;  acc[5] += a1 * b1v;  acc[6] += a1 * b2v;  acc[7] += a1 * b3;
        acc[8] += a2 * b0;  acc[9] += a2 * b1v;  acc[10] += a2 * b2v; acc[11] += a2 * b3;
        acc[12] += a3 * b0; acc[13] += a3 * b1v; acc[14] += a3 * b2v; acc[15] += a3 * b3;
      }
      __syncthreads();                       // all reads of sT done
      const float cd = coef[d - 2];
      #pragma unroll
      for (int rr = 0; rr < 4; ++rr)
        #pragma unroll
        for (int c = 0; c < 4; ++c) {
          sT[(r0 + rr) * LD + c0 + c] = acc[rr * 4 + c];
          E[rr * 4 + c] += cd * acc[rr * 4 + c];
        }
      __syncthreads();
    }
    // E -> sT
    #pragma unroll
    for (int rr = 0; rr < 4; ++rr)
      #pragma unroll
      for (int c = 0; c < 4; ++c)
        sT[(r0 + rr) * LD + c0 + c] = E[rr * 4 + c];
    __syncthreads();
    // square k times (in place via register staging)
    for (int itq = 0; itq < kpow; ++itq) {
      float acc[16];
      #pragma unroll
      for (int u = 0; u < 16; ++u) acc[u] = 0.0f;
      for (int kk = 0; kk < 64; ++kk) {
        float a0 = sT[(r0 + 0) * LD + kk], a1 = sT[(r0 + 1) * LD + kk];
        float a2 = sT[(r0 + 2) * LD + kk], a3 = sT[(r0 + 3) * LD + kk];
        float b0 = sT[kk * LD + c0 + 0], b1v = sT[kk * LD + c0 + 1];
        float b2v = sT[kk * LD + c0 + 2], b3 = sT[kk * LD + c0 + 3];
        acc[0] += a0 * b0;  acc[1] += a0 * b1v;  acc[2] += a0 * b2v;  acc[3] += a0 * b3;
        acc[4] += a1 * b0;  acc[5] += a1 * b1v;  acc[6] += a1 * b2v;  acc[7] += a1 * b3;
        acc[8] += a2 * b0;  acc[9] += a2 * b1v;  acc[10] += a2 * b2v; acc[11] += a2 * b3;
        acc[12] += a3 * b0; acc[13] += a3 * b1v; acc[14] += a3 * b2v; acc[15] += a3 * b3;
      }
      __syncthreads();
      #pragma unroll
      for (int rr = 0; rr < 4; ++rr)
        #pragma unroll
        for (int c = 0; c < 4; ++c)
          sT[(r0 + rr) * LD + c0 + c] = acc[rr * 4 + c];
      __syncthreads();
    }
  }
  // exp_a now in sT

  gemm_gS(ref, sT, sA);           // A = M2 = ref @ exp_a
  __syncthreads();

  // --- SPD shift: shift = max(EPS - lambda_min(sym_lower(M2)), 0)
  // Fast path: LDL^T PD-test of C = sym_lower(M2) - EPS*I (workspace sT).
  {
    for (int idx = tid; idx < 4096; idx += BLOCK) {
      int i = idx >> 6, jj = idx & 63;
      float v = (i >= jj) ? sA[i * LD + jj] : sA[jj * LD + i];
      sT[i * LD + jj] = v - ((i == jj) ? EPSF : 0.0f);
    }
    __syncthreads();

    bool pd = true;
    const int col = tid & 63;
    const int rw  = tid >> 6;
    for (int k = 0; k < 64; ++k) {
      float d = sT[k * LD + k];
      if (d <= 1e-30f) { pd = false; break; }
      if (col > k) {
        float ljk = sT[col * LD + k] / d;
        for (int i = k + 1 + rw; i < 64; i += 4) {
          float aik = sT[i * LD + k];
          sT[i * LD + col] -= aik * ljk;
        }
      }
      __syncthreads();
    }

    if (pd) {
      if (tid == 0) shiftv = 0.0f;
      __syncthreads();
    } else {
      __syncthreads();
      // Fallback: eigenvalues-only Jacobi on sym_lower(M2)
      for (int idx = tid; idx < 4096; idx += BLOCK) {
        int i = idx >> 6, jj = idx & 63;
        sT[i * LD + jj] = (i >= jj) ? sA[i * LD + jj] : sA[jj * LD + i];
      }
      __syncthreads();
      jacobi64<false>(sT, nullptr, red, RELTOL_VALS);
      if (tid == 0) {
        float mn = sT[0];
        for (int i = 1; i < 64; ++i) mn = fminf(mn, sT[i * LD + i]);
        shiftv = fmaxf(EPSF - mn, 0.0f);
      }
      __syncthreads();
    }
  }

  const float sh = shiftv;
  for (int idx = tid; idx < 4096; idx += BLOCK) {
    int i = idx >> 6, jj = idx & 63;
    out[b * 4096 + idx] = sA[i * LD + jj] + ((i == jj) ? sh : 0.0f);
  }
}

extern "C" void kernel_launch(void* const* d_in, const int* in_sizes, int n_in,
                              void* d_out, int out_size, void* d_ws, size_t ws_size,
                              hipStream_t stream) {
  (void)in_sizes; (void)n_in; (void)out_size; (void)ws_size;
  const float* x    = (const float*)d_in[0];
  const float* ref  = (const float*)d_in[1];
  const float* w1   = (const float*)d_in[2];
  const float* b1   = (const float*)d_in[3];
  const float* g1   = (const float*)d_in[4];
  const float* bb1  = (const float*)d_in[5];
  const float* w2   = (const float*)d_in[6];
  const float* b2   = (const float*)d_in[7];
  const float* g2   = (const float*)d_in[8];
  const float* bb2  = (const float*)d_in[9];
  const float* muw  = (const float*)d_in[10];
  const float* mub  = (const float*)d_in[11];
  const float* lvw  = (const float*)d_in[12];
  const float* lvb  = (const float*)d_in[13];
  const float* dw1  = (const float*)d_in[14];
  const float* db1  = (const float*)d_in[15];
  const float* dg1  = (const float*)d_in[16];
  const float* dbb1 = (const float*)d_in[17];
  const float* dw2  = (const float*)d_in[18];
  const float* db2  = (const float*)d_in[19];
  const float* dg2  = (const float*)d_in[20];
  const float* dbb2 = (const float*)d_in[21];
  const float* dw3  = (const float*)d_in[22];
  const float* db3  = (const float*)d_in[23];
  float* out = (float*)d_out;
  float* ws  = (float*)d_ws;   // rm (4096 floats) + rp (4096 floats)

  vae_prep<<<1, BLOCK, 0, stream>>>(ref, ws);
  vae_main<<<BATCH, BLOCK, 0, stream>>>(x, ref, ws,
      w1, b1, g1, bb1, w2, b2, g2, bb2, muw, mub, lvw, lvb,
      dw1, db1, dg1, dbb1, dw2, db2, dg2, dbb2, dw3, db3, out);
}

// Round 9
// 7179.464 us; speedup vs baseline: 2.1742x; 2.1742x over previous
//
#include <hip/hip_runtime.h>

#define NN 64
#define LD 65            // odd stride: 65 % 32 == 1 -> lane-vs-row access is 2-way (free).
                         // LD=66 measured 6.9x bank conflicts (4-way) -> keep 65.
#define NPAIR 32
#define BLOCK 256
#define MAXSWEEP 11
#define EPSF 1e-6f
#define TRI 2080
#define BATCH 4096
#define MU_OFF 16777216
#define LV_OFF 16908288
#define RELTOL_MAIN 1e-8f
#define RELTOL_PREP 1e-12f
#define RELTOL_VALS 1e-8f

__device__ __forceinline__ int triOff(int i) { return (i * (129 - i)) >> 1; }

__device__ __forceinline__ float bn_leaky(float h, float g, float bb) {
  h = (h >= 0.0f) ? h : 0.2f * h;
  return h * (1.0f / sqrtf(1.0f + 1e-5f)) * g + bb;
}

// Parallel cyclic Jacobi eigensolver, 64x64 symmetric in LDS (ld 65).
// XOR 1-factorization: round m = 1..63 pairs i with i^m. Two-phase update,
// lane = column: row phase conflict-free, col phase exact 2-way (free, LD=65).
// Measured (r8): bank conflicts 1.74e9 -> 9.6e7 vs the 2x2-block scheme. BUT
// VGPR hit 136 -> occupancy halved (22%->11.8%, m69 cliff at 128) -> 15.0ms.
// Fix: __launch_bounds__(256,4) caps VGPR at 128 -> 4 waves/SIMD restored.
// Angles in-wave (lanes 0-7 + shfl broadcast; safe: a wave's angle reads touch
// only rows it alone writes). 2 barriers/round. off^2 convergence accumulated
// free from the last round's col-phase writes (cols partition the matrix).
// On exit: diag(A) = eigenvalues (unsorted), V = eigenvectors (cols), if WITH_V.
template<bool WITH_V>
__device__ void jacobi64(float* A, float* V, float* red, float relTol)
{
  const int tid = threadIdx.x;
  const int w   = tid >> 6;   // wave id 0..3
  const int j   = tid & 63;   // lane

  if (WITH_V) {
    for (int idx = tid; idx < NN * LD; idx += BLOCK) V[idx] = 0.0f;
    __syncthreads();
    if (tid < NN) V[tid * LD + tid] = 1.0f;
  }

  // Frobenius^2 (rotation invariant) -> tolerance
  float fp = 0.0f;
  for (int idx = tid; idx < NN * NN; idx += BLOCK) {
    float a = A[(idx >> 6) * LD + (idx & 63)];
    fp += a * a;
  }
  #pragma unroll
  for (int o = 32; o > 0; o >>= 1) fp += __shfl_xor(fp, o);
  if (j == 0) red[w] = fp;
  __syncthreads();          // also makes V diag writes visible
  const float tol = (red[0] + red[1] + red[2] + red[3]) * relTol + 1e-30f;

  for (int sweep = 0; sweep < MAXSWEEP; ++sweep) {
    for (int m = 1; m < 64; ++m) {
      const int b  = 31 - __clz(m);          // wave-uniform
      const int lm = (1 << b) - 1;

      // --- in-wave angles: every lane computes pair kk = 8w + (j&7) ---
      // (8-way same-address reads = LDS broadcast, free; no extra barrier:
      //  these rows are written only by THIS wave's row phase, after the reads)
      const int kk = (w << 3) + (j & 7);
      const int pk = ((kk >> b) << (b + 1)) | (kk & lm);   // bit b clear
      const int qk = pk ^ m;
      float app = A[pk * LD + pk];
      float aqq = A[qk * LD + qk];
      float apq = A[pk * LD + qk];
      float cv = 1.0f, sv = 0.0f;
      if (fabsf(apq) > 1e-36f) {
        float th = (aqq - app) / (2.0f * apq);
        float t  = 1.0f / (fabsf(th) + sqrtf(th * th + 1.0f));
        if (th < 0.0f) t = -t;
        cv = 1.0f / sqrtf(t * t + 1.0f);
        sv = t * cv;
      }

      float cc[8], ss[8]; int pp[8], qq[8];
      #pragma unroll
      for (int it = 0; it < 8; ++it) {
        cc[it] = __shfl(cv, it);             // lane it computed pair 8w+it
        ss[it] = __shfl(sv, it);
        const int k2 = (w << 3) + it;
        pp[it] = ((k2 >> b) << (b + 1)) | (k2 & lm);
        qq[it] = pp[it] ^ m;
      }

      // --- row phase: rows of our 8 pairs, col = j (batched, unconditional) ---
      float ap[8], aq[8];
      #pragma unroll
      for (int it = 0; it < 8; ++it) {
        ap[it] = A[pp[it] * LD + j];
        aq[it] = A[qq[it] * LD + j];
      }
      #pragma unroll
      for (int it = 0; it < 8; ++it) {
        A[pp[it] * LD + j] = cc[it] * ap[it] - ss[it] * aq[it];
        A[qq[it] * LD + j] = ss[it] * ap[it] + cc[it] * aq[it];
      }
      __syncthreads();

      // --- col phase (+ V), same 8 pairs, row = j ---
      float lo = 0.0f;
      #pragma unroll
      for (int it = 0; it < 8; ++it) {
        ap[it] = A[j * LD + pp[it]];
        aq[it] = A[j * LD + qq[it]];
      }
      #pragma unroll
      for (int it = 0; it < 8; ++it) {
        float np = cc[it] * ap[it] - ss[it] * aq[it];
        float nq = ss[it] * ap[it] + cc[it] * aq[it];
        A[j * LD + pp[it]] = np;
        A[j * LD + qq[it]] = nq;
        if (m == 63) {                       // free off^2 on the sweep's last round
          if (j != pp[it]) lo += np * np;
          if (j != qq[it]) lo += nq * nq;
        }
      }
      if (WITH_V) {
        float vp[8], vq[8];
        #pragma unroll
        for (int it = 0; it < 8; ++it) {
          vp[it] = V[j * LD + pp[it]];
          vq[it] = V[j * LD + qq[it]];
        }
        #pragma unroll
        for (int it = 0; it < 8; ++it) {
          V[j * LD + pp[it]] = cc[it] * vp[it] - ss[it] * vq[it];
          V[j * LD + qq[it]] = ss[it] * vp[it] + cc[it] * vq[it];
        }
      }
      if (m == 63) {
        #pragma unroll
        for (int o = 32; o > 0; o >>= 1) lo += __shfl_xor(lo, o);
        if (j == 0) red[w] = lo;
      }
      __syncthreads();
    }
    const float off2 = red[0] + red[1] + red[2] + red[3];
    if (off2 <= tol) break;     // uniform
  }
  __syncthreads();
}

// O = Lg @ S ; Lg global row-major 64 (wave-uniform scalar loads), S LDS (ld 65).
__device__ void gemm_gS(const float* __restrict__ Lg, const float* S, float* O)
{
  const int tid = threadIdx.x;
  const int j  = tid & 63;
  const int iw = __builtin_amdgcn_readfirstlane((tid >> 6) << 4);
  float acc[16];
  #pragma unroll
  for (int ii = 0; ii < 16; ++ii) acc[ii] = 0.0f;
  for (int kb = 0; kb < 64; kb += 4) {
    float sv0 = S[(kb + 0) * LD + j];
    float sv1 = S[(kb + 1) * LD + j];
    float sv2 = S[(kb + 2) * LD + j];
    float sv3 = S[(kb + 3) * LD + j];
    #pragma unroll
    for (int ii = 0; ii < 16; ++ii) {
      const float* lr = Lg + (iw + ii) * 64 + kb;   // wave-uniform -> s_load
      acc[ii] += lr[0] * sv0 + lr[1] * sv1 + lr[2] * sv2 + lr[3] * sv3;
    }
  }
  #pragma unroll
  for (int ii = 0; ii < 16; ++ii) O[(iw + ii) * LD + j] = acc[ii];
}

// O = S @ Rg with Rg SYMMETRIC global (rows, wave-uniform scalar):
// O[i][j] = sum_k S[i][k]*Rg[j*64+k]
__device__ void gemm_SgT(const float* S, const float* __restrict__ Rg, float* O)
{
  const int tid = threadIdx.x;
  const int i  = tid & 63;
  const int jw = __builtin_amdgcn_readfirstlane((tid >> 6) << 4);
  float acc[16];
  #pragma unroll
  for (int jj = 0; jj < 16; ++jj) acc[jj] = 0.0f;
  for (int kb = 0; kb < 64; kb += 4) {
    float s0 = S[i * LD + kb + 0];
    float s1 = S[i * LD + kb + 1];
    float s2 = S[i * LD + kb + 2];
    float s3 = S[i * LD + kb + 3];
    #pragma unroll
    for (int jj = 0; jj < 16; ++jj) {
      const float* rr = Rg + (jw + jj) * 64 + kb;   // wave-uniform -> s_load
      acc[jj] += s0 * rr[0] + s1 * rr[1] + s2 * rr[2] + s3 * rr[3];
    }
  }
  #pragma unroll
  for (int jj = 0; jj < 16; ++jj) O[i * LD + jw + jj] = acc[jj];
}

// O[i][j] = sum_k P[i][k] * w[k] * V[j][k]  (all LDS). O may alias V or P.
__device__ void gemm_ADT(const float* P, const float* w, const float* V, float* O)
{
  const int tid = threadIdx.x;
  const int i  = tid & 63;
  const int jw = __builtin_amdgcn_readfirstlane((tid >> 6) << 4);
  float acc[16];
  #pragma unroll
  for (int jj = 0; jj < 16; ++jj) acc[jj] = 0.0f;
  for (int k = 0; k < 64; ++k) {
    float pw = P[i * LD + k] * w[k];
    #pragma unroll
    for (int jj = 0; jj < 16; ++jj) acc[jj] += pw * V[(jw + jj) * LD + k];
  }
  __syncthreads();
  #pragma unroll
  for (int jj = 0; jj < 16; ++jj) O[i * LD + jw + jj] = acc[jj];
}

// --- prep: eigh(ref + eps I) -> rm = ref^{-1/2}, rp = ref^{1/2} into ws ---
__global__ __launch_bounds__(BLOCK, 4) void vae_prep(const float* __restrict__ ref,
                                                     float* __restrict__ rmrp)
{
  __shared__ __align__(16) float sA[NN * LD];
  __shared__ __align__(16) float sT[NN * LD];
  __shared__ float red[BLOCK];
  __shared__ float wb[64];
  const int tid = threadIdx.x;

  for (int idx = tid; idx < NN * NN; idx += BLOCK) {
    int i = idx >> 6, j = idx & 63;
    sA[i * LD + j] = ref[idx] + ((i == j) ? EPSF : 0.0f);
  }
  __syncthreads();
  jacobi64<true>(sA, sT, red, RELTOL_PREP);
  if (tid < 64) wb[tid] = sA[tid * LD + tid];
  __syncthreads();

  const int i  = tid & 63;
  const int jw = (tid >> 6) << 4;
  float am[16], aps[16];
  #pragma unroll
  for (int jj = 0; jj < 16; ++jj) { am[jj] = 0.0f; aps[jj] = 0.0f; }
  for (int k = 0; k < 64; ++k) {
    float vik = sT[i * LD + k];
    float wk  = wb[k];
    float rs  = 1.0f / sqrtf(wk);   // ref SPD: wk >= ~0.5
    float sq  = sqrtf(wk);
    float pr = vik * rs, pq = vik * sq;
    #pragma unroll
    for (int jj = 0; jj < 16; ++jj) {
      float vjk = sT[(jw + jj) * LD + k];
      am[jj]  += pr * vjk;
      aps[jj] += pq * vjk;
    }
  }
  #pragma unroll
  for (int jj = 0; jj < 16; ++jj) {
    rmrp[i * 64 + jw + jj]        = am[jj];
    rmrp[4096 + i * 64 + jw + jj] = aps[jj];
  }
}

// --- main: one block per batch item, fully fused ---
__global__ __launch_bounds__(BLOCK, 4) void vae_main(
    const float* __restrict__ x,   const float* __restrict__ ref,
    const float* __restrict__ rmrp,
    const float* __restrict__ w1,  const float* __restrict__ b1,
    const float* __restrict__ g1,  const float* __restrict__ bb1,
    const float* __restrict__ w2,  const float* __restrict__ b2,
    const float* __restrict__ g2,  const float* __restrict__ bb2,
    const float* __restrict__ muw, const float* __restrict__ mub,
    const float* __restrict__ lvw, const float* __restrict__ lvb,
    const float* __restrict__ dw1, const float* __restrict__ db1,
    const float* __restrict__ dg1, const float* __restrict__ dbb1,
    const float* __restrict__ dw2, const float* __restrict__ db2,
    const float* __restrict__ dg2, const float* __restrict__ dbb2,
    const float* __restrict__ dw3, const float* __restrict__ db3,
    float* __restrict__ out)
{
  __shared__ __align__(16) float sA[NN * LD];
  __shared__ __align__(16) float sT[NN * LD];   // also hosts svec (2080 <= 4160)
  __shared__ float red[BLOCK];
  __shared__ float h1s[128], h2s[64], zs[32], d1s[64], d2s[128];
  __shared__ float wb[64];
  __shared__ float shiftv;

  const int tid = threadIdx.x;
  const int b   = blockIdx.x;
  const float* rm = rmrp;
  const float* rp = rmrp + 4096;
  float* svec = sT;   // alias: sT is dead during the MLP phase

  // load x (shift for _ensure_spd(x) is provably 0: lambda_min(x) >= 0.5)
  for (int idx = tid; idx < 4096; idx += BLOCK)
    sA[(idx >> 6) * LD + (idx & 63)] = x[b * 4096 + idx];
  __syncthreads();

  gemm_gS(rm, sA, sT);            // T = rm @ x
  __syncthreads();
  gemm_SgT(sT, rm, sA);           // A = T @ rm = s
  __syncthreads();

  jacobi64<true>(sA, sT, red, RELTOL_MAIN);  // s = V w V^T (V in sT)
  if (tid < 64) wb[tid] = logf(fmaxf(sA[tid * LD + tid], 1e-12f));
  __syncthreads();

  gemm_gS(rm, sT, sA);            // A = rm @ V
  __syncthreads();
  gemm_ADT(sA, wb, sT, sT);       // T = (rm V) diag(log w) V^T  (alias-safe)
  __syncthreads();
  gemm_SgT(sT, rp, sA);           // A = tang = T @ rp
  __syncthreads();

  // vec = upper-triangle of tang (row-major triu order) -> svec (in sT)
  for (int idx = tid; idx < TRI; idx += BLOCK) {
    int i = (int)((129.0f - sqrtf(16641.0f - 8.0f * (float)idx)) * 0.5f);
    while (triOff(i + 1) <= idx) ++i;
    while (triOff(i) > idx) --i;
    int jj = i + (idx - triOff(i));
    svec[idx] = sA[i * LD + jj];
  }
  __syncthreads();

  // encoder L1: 2080 -> 128
  {
    int o = tid & 127, half = tid >> 7;
    const float4* wr = (const float4*)(w1 + o * 2080 + half * 1040);
    const float4* vv = (const float4*)(svec + half * 1040);
    float acc = 0.0f;
    for (int i4 = 0; i4 < 260; ++i4) {
      float4 a = wr[i4], v4 = vv[i4];
      acc += a.x * v4.x + a.y * v4.y + a.z * v4.z + a.w * v4.w;
    }
    red[tid] = acc;
    __syncthreads();
    if (tid < 128)
      h1s[tid] = bn_leaky(red[tid] + red[tid + 128] + b1[tid], g1[tid], bb1[tid]);
    __syncthreads();
  }
  // encoder L2: 128 -> 64
  {
    int o = tid & 63, half = tid >> 6;
    const float* wr = w2 + o * 128 + half * 32;
    const float* hh = h1s + half * 32;
    float acc = 0.0f;
    #pragma unroll 8
    for (int i = 0; i < 32; ++i) acc += wr[i] * hh[i];
    red[tid] = acc;
    __syncthreads();
    if (tid < 64)
      h2s[tid] = bn_leaky(red[tid] + red[tid + 64] + red[tid + 128] + red[tid + 192] + b2[tid],
                          g2[tid], bb2[tid]);
    __syncthreads();
  }
  // mu / logvar: 64 -> 32 each (z = mu)
  if (tid < 64) {
    int o = tid & 31;
    const float* wr = (tid < 32 ? muw : lvw) + o * 64;
    float acc = (tid < 32 ? mub : lvb)[o];
    for (int i = 0; i < 64; ++i) acc += wr[i] * h2s[i];
    if (tid < 32) { zs[o] = acc; out[MU_OFF + b * 32 + o] = acc; }
    else          { out[LV_OFF + b * 32 + o] = acc; }
  }
  __syncthreads();
  // decoder L1: 32 -> 64
  if (tid < 64) {
    const float* wr = dw1 + tid * 32;
    float acc = db1[tid];
    for (int i = 0; i < 32; ++i) acc += wr[i] * zs[i];
    d1s[tid] = bn_leaky(acc, dg1[tid], dbb1[tid]);
  }
  __syncthreads();
  // decoder L2: 64 -> 128
  if (tid < 128) {
    const float* wr = dw2 + tid * 64;
    float acc = db2[tid];
    for (int i = 0; i < 64; ++i) acc += wr[i] * d1s[i];
    d2s[tid] = bn_leaky(acc, dg2[tid], dbb2[tid]);
  }
  __syncthreads();
  // decoder L3: 128 -> 2080 (vdec into svec)
  for (int o = tid; o < TRI; o += BLOCK) {
    const float4* wr = (const float4*)(dw3 + o * 128);
    float acc = db3[o];
    #pragma unroll 8
    for (int k4 = 0; k4 < 32; ++k4) {
      float4 a = wr[k4];
      acc += a.x * d2s[k4 * 4] + a.y * d2s[k4 * 4 + 1] + a.z * d2s[k4 * 4 + 2] + a.w * d2s[k4 * 4 + 3];
    }
    svec[o] = acc;
  }
  __syncthreads();

  // mtil = symmetric(vdec) + eps I  -> sA
  for (int idx = tid; idx < 4096; idx += BLOCK) {
    int i = idx >> 6, jj = idx & 63;
    int lo = (i < jj) ? i : jj, hi = (i < jj) ? jj : i;
    sA[i * LD + jj] = svec[triOff(lo) + (hi - lo)] + ((i == jj) ? EPSF : 0.0f);
  }
  __syncthreads();

  // ===== exp(mtil) via scaling & squaring (replaces 2nd Jacobi eigh) =====
  {
    const int ti = tid >> 4;          // 0..15 (row tile)
    const int tj = tid & 15;          // 0..15 (col tile)
    const int r0 = ti << 2, c0 = tj << 2;

    // inf-norm (symmetric => bounds spectral norm)
    if (tid < 64) {
      float rs = 0.0f;
      for (int jj2 = 0; jj2 < 64; ++jj2) rs += fabsf(sA[tid * LD + jj2]);
      red[tid] = rs;
    }
    __syncthreads();
    if (tid < 32) red[tid] = fmaxf(red[tid], red[tid + 32]);
    __syncthreads();
    if (tid < 16) red[tid] = fmaxf(red[tid], red[tid + 16]);
    __syncthreads();
    if (tid < 8)  red[tid] = fmaxf(red[tid], red[tid + 8]);
    __syncthreads();
    if (tid < 4)  red[tid] = fmaxf(fmaxf(red[tid], red[tid + 4]),
                                   fmaxf(red[tid + 2] , red[(tid + 2) & 3]));
    __syncthreads();
    float R = fmaxf(fmaxf(red[0], red[1]), fmaxf(red[2], red[3]));

    int kpow = 0;
    float t = R;
    while (t > 0.25f && kpow < 24) { t *= 0.5f; ++kpow; }
    const float sc = ldexpf(1.0f, -kpow);

    // X = mtil * 2^-k (in place, sA)
    for (int idx = tid; idx < 4096; idx += BLOCK) {
      int i = idx >> 6, jj = idx & 63;
      sA[i * LD + jj] *= sc;
    }
    __syncthreads();

    // E = I + X + sum_{d=2..8} X^d/d!   (E in registers, powers ping in sT)
    float E[16];
    #pragma unroll
    for (int rr = 0; rr < 4; ++rr)
      #pragma unroll
      for (int c = 0; c < 4; ++c)
        E[rr * 4 + c] = ((r0 + rr) == (c0 + c) ? 1.0f : 0.0f) + sA[(r0 + rr) * LD + c0 + c];

    const float coef[7] = { 0.5f, 0.16666667f, 0.041666668f, 0.008333334f,
                            0.0013888889f, 1.9841270e-4f, 2.4801587e-5f };

    // d = 2: P = X*X  (reads sA only; sT dead after svec consumed)
    {
      float acc[16];
      #pragma unroll
      for (int u = 0; u < 16; ++u) acc[u] = 0.0f;
      for (int kk = 0; kk < 64; ++kk) {
        float a0 = sA[(r0 + 0) * LD + kk], a1 = sA[(r0 + 1) * LD + kk];
        float a2 = sA[(r0 + 2) * LD + kk], a3 = sA[(r0 + 3) * LD + kk];
        float b0 = sA[kk * LD + c0 + 0], b1v = sA[kk * LD + c0 + 1];
        float b2v = sA[kk * LD + c0 + 2], b3 = sA[kk * LD + c0 + 3];
        acc[0] += a0 * b0;  acc[1] += a0 * b1v;  acc[2] += a0 * b2v;  acc[3] += a0 * b3;
        acc[4] += a1 * b0;  acc[5] += a1 * b1v;  acc[6] += a1 * b2v;  acc[7] += a1 * b3;
        acc[8] += a2 * b0;  acc[9] += a2 * b1v;  acc[10] += a2 * b2v; acc[11] += a2 * b3;
        acc[12] += a3 * b0; acc[13] += a3 * b1v; acc[14] += a3 * b2v; acc[15] += a3 * b3;
      }
      __syncthreads();
      #pragma unroll
      for (int rr = 0; rr < 4; ++rr)
        #pragma unroll
        for (int c = 0; c < 4; ++c) {
          sT[(r0 + rr) * LD + c0 + c] = acc[rr * 4 + c];
          E[rr * 4 + c] += coef[0] * acc[rr * 4 + c];
        }
      __syncthreads();
    }
    // d = 3..8: P = P*X (in place via register staging)
    for (int d = 3; d <= 8; ++d) {
      float acc[16];
      #pragma unroll
      for (int u = 0; u < 16; ++u) acc[u] = 0.0f;
      for (int kk = 0; kk < 64; ++kk) {
        float a0 = sT[(r0 + 0) * LD + kk], a1 = sT[(r0 + 1) * LD + kk];
        float a2 = sT[(r0 + 2) * LD + kk], a3 = sT[(r0 + 3) * LD + kk];
        float b0 = sA[kk * LD + c0 + 0], b1v = sA[kk * LD + c0 + 1];
        float b2v = sA[kk * LD + c0 + 2], b3 = sA[kk * LD + c0 + 3];
        acc[0] += a0 * b0;  acc[1] += a0 * b1v;  acc[2] += a0 * b2v;  acc[3] += a0 * b3;
        acc[4] += a1 * b0;  acc[5] += a1 * b1v;  acc[6] += a1 * b2v;  acc[7] += a1 * b3;
        acc[8] += a2 * b0;  acc[9] += a2 * b1v;  acc[10] += a2 * b2v; acc[11] += a2 * b3;
        acc[12] += a3 * b0; acc[13] += a3 * b1v; acc[14] += a3 * b2v; acc[15] += a3 * b3;
      }
      __syncthreads();                       // all reads of sT done
      const float cd = coef[d - 2];
      #pragma unroll
      for (int rr = 0; rr < 4; ++rr)
        #pragma unroll
        for (int c = 0; c < 4; ++c) {
          sT[(r0 + rr) * LD + c0 + c] = acc[rr * 4 + c];
          E[rr * 4 + c] += cd * acc[rr * 4 + c];
        }
      __syncthreads();
    }
    // E -> sT
    #pragma unroll
    for (int rr = 0; rr < 4; ++rr)
      #pragma unroll
      for (int c = 0; c < 4; ++c)
        sT[(r0 + rr) * LD + c0 + c] = E[rr * 4 + c];
    __syncthreads();
    // square k times (in place via register staging)
    for (int itq = 0; itq < kpow; ++itq) {
      float acc[16];
      #pragma unroll
      for (int u = 0; u < 16; ++u) acc[u] = 0.0f;
      for (int kk = 0; kk < 64; ++kk) {
        float a0 = sT[(r0 + 0) * LD + kk], a1 = sT[(r0 + 1) * LD + kk];
        float a2 = sT[(r0 + 2) * LD + kk], a3 = sT[(r0 + 3) * LD + kk];
        float b0 = sT[kk * LD + c0 + 0], b1v = sT[kk * LD + c0 + 1];
        float b2v = sT[kk * LD + c0 + 2], b3 = sT[kk * LD + c0 + 3];
        acc[0] += a0 * b0;  acc[1] += a0 * b1v;  acc[2] += a0 * b2v;  acc[3] += a0 * b3;
        acc[4] += a1 * b0;  acc[5] += a1 * b1v;  acc[6] += a1 * b2v;  acc[7] += a1 * b3;
        acc[8] += a2 * b0;  acc[9] += a2 * b1v;  acc[10] += a2 * b2v; acc[11] += a2 * b3;
        acc[12] += a3 * b0; acc[13] += a3 * b1v; acc[14] += a3 * b2v; acc[15] += a3 * b3;
      }
      __syncthreads();
      #pragma unroll
      for (int rr = 0; rr < 4; ++rr)
        #pragma unroll
        for (int c = 0; c < 4; ++c)
          sT[(r0 + rr) * LD + c0 + c] = acc[rr * 4 + c];
      __syncthreads();
    }
  }
  // exp_a now in sT

  gemm_gS(ref, sT, sA);           // A = M2 = ref @ exp_a
  __syncthreads();

  // --- SPD shift: shift = max(EPS - lambda_min(sym_lower(M2)), 0)
  // Fast path: LDL^T PD-test of C = sym_lower(M2) - EPS*I (workspace sT).
  {
    for (int idx = tid; idx < 4096; idx += BLOCK) {
      int i = idx >> 6, jj = idx & 63;
      float v = (i >= jj) ? sA[i * LD + jj] : sA[jj * LD + i];
      sT[i * LD + jj] = v - ((i == jj) ? EPSF : 0.0f);
    }
    __syncthreads();

    bool pd = true;
    const int col = tid & 63;
    const int rw  = tid >> 6;
    for (int k = 0; k < 64; ++k) {
      float d = sT[k * LD + k];
      if (d <= 1e-30f) { pd = false; break; }
      if (col > k) {
        float ljk = sT[col * LD + k] / d;
        for (int i = k + 1 + rw; i < 64; i += 4) {
          float aik = sT[i * LD + k];
          sT[i * LD + col] -= aik * ljk;
        }
      }
      __syncthreads();
    }

    if (pd) {
      if (tid == 0) shiftv = 0.0f;
      __syncthreads();
    } else {
      __syncthreads();
      // Fallback: eigenvalues-only Jacobi on sym_lower(M2)
      for (int idx = tid; idx < 4096; idx += BLOCK) {
        int i = idx >> 6, jj = idx & 63;
        sT[i * LD + jj] = (i >= jj) ? sA[i * LD + jj] : sA[jj * LD + i];
      }
      __syncthreads();
      jacobi64<false>(sT, nullptr, red, RELTOL_VALS);
      if (tid == 0) {
        float mn = sT[0];
        for (int i = 1; i < 64; ++i) mn = fminf(mn, sT[i * LD + i]);
        shiftv = fmaxf(EPSF - mn, 0.0f);
      }
      __syncthreads();
    }
  }

  const float sh = shiftv;
  for (int idx = tid; idx < 4096; idx += BLOCK) {
    int i = idx >> 6, jj = idx & 63;
    out[b * 4096 + idx] = sA[i * LD + jj] + ((i == jj) ? sh : 0.0f);
  }
}

extern "C" void kernel_launch(void* const* d_in, const int* in_sizes, int n_in,
                              void* d_out, int out_size, void* d_ws, size_t ws_size,
                              hipStream_t stream) {
  (void)in_sizes; (void)n_in; (void)out_size; (void)ws_size;
  const float* x    = (const float*)d_in[0];
  const float* ref  = (const float*)d_in[1];
  const float* w1   = (const float*)d_in[2];
  const float* b1   = (const float*)d_in[3];
  const float* g1   = (const float*)d_in[4];
  const float* bb1  = (const float*)d_in[5];
  const float* w2   = (const float*)d_in[6];
  const float* b2   = (const float*)d_in[7];
  const float* g2   = (const float*)d_in[8];
  const float* bb2  = (const float*)d_in[9];
  const float* muw  = (const float*)d_in[10];
  const float* mub  = (const float*)d_in[11];
  const float* lvw  = (const float*)d_in[12];
  const float* lvb  = (const float*)d_in[13];
  const float* dw1  = (const float*)d_in[14];
  const float* db1  = (const float*)d_in[15];
  const float* dg1  = (const float*)d_in[16];
  const float* dbb1 = (const float*)d_in[17];
  const float* dw2  = (const float*)d_in[18];
  const float* db2  = (const float*)d_in[19];
  const float* dg2  = (const float*)d_in[20];
  const float* dbb2 = (const float*)d_in[21];
  const float* dw3  = (const float*)d_in[22];
  const float* db3  = (const float*)d_in[23];
  float* out = (float*)d_out;
  float* ws  = (float*)d_ws;   // rm (4096 floats) + rp (4096 floats)

  vae_prep<<<1, BLOCK, 0, stream>>>(ref, ws);
  vae_main<<<BATCH, BLOCK, 0, stream>>>(x, ref, ws,
      w1, b1, g1, bb1, w2, b2, g2, bb2, muw, mub, lvw, lvb,
      dw1, db1, dg1, dbb1, dw2, db2, dg2, dbb2, dw3, db3, out);
}

// Round 11
// 7174.825 us; speedup vs baseline: 2.1756x; 1.0006x over previous
//
#include <hip/hip_runtime.h>

#define NN 64
#define LD 65            // odd stride: 65 % 32 == 1 -> lane-vs-row access is 2-way (free).
#define NPAIR 32
#define BLOCK 256
#define MAXSWEEP 11
#define EPSF 1e-6f
#define TRI 2080
#define BATCH 4096
#define MU_OFF 16777216
#define LV_OFF 16908288
#define RELTOL_MAIN 1e-8f
#define RELTOL_PREP 1e-12f
#define RELTOL_VALS 1e-8f

__device__ __forceinline__ int triOff(int i) { return (i * (129 - i)) >> 1; }

__device__ __forceinline__ float bn_leaky(float h, float g, float bb) {
  h = (h >= 0.0f) ? h : 0.2f * h;
  return h * (1.0f / sqrtf(1.0f + 1e-5f)) * g + bb;
}

// Parallel cyclic Jacobi eigensolver, 64x64 symmetric in LDS (ld 65).
// XOR 1-factorization: round m pairs i with i^m; rep p has top-bit-of-m clear.
// Two-phase, lane = column: row phase conflict-free; col phase exact 2-way (free).
// History: 2x2-block scheme = 1.74e9 bank conflicts (r6); XOR fixed that (9.6e7)
// but VGPR 136 halved occupancy (r8, 15ms); launch_bounds(256,4) restored occ
// (43%, 7.2ms) but allocator clamped to 64 VGPR and SPILLED (FETCH 42->831 MB).
// This version halves the register working set so it fits WITHOUT spills:
//  - p,q recomputed from XOR (3 int ops), never stored 8-wide
//  - angles __shfl'd per 4-pair batch; row/col/V phases in 2 batches of 4
// Batches touch disjoint rows/cols -> no new hazards; 2 barriers/round kept.
// off^2 convergence accumulated free from last round's col-phase writes.
// On exit: diag(A) = eigenvalues (unsorted), V = eigenvectors (cols), if WITH_V.
template<bool WITH_V>
__device__ void jacobi64(float* A, float* V, float* red, float relTol)
{
  const int tid = threadIdx.x;
  const int w   = tid >> 6;   // wave id 0..3
  const int j   = tid & 63;   // lane

  if (WITH_V) {
    for (int idx = tid; idx < NN * LD; idx += BLOCK) V[idx] = 0.0f;
    __syncthreads();
    if (tid < NN) V[tid * LD + tid] = 1.0f;
  }

  // Frobenius^2 (rotation invariant) -> tolerance
  float fp = 0.0f;
  for (int idx = tid; idx < NN * NN; idx += BLOCK) {
    float a = A[(idx >> 6) * LD + (idx & 63)];
    fp += a * a;
  }
  #pragma unroll
  for (int o = 32; o > 0; o >>= 1) fp += __shfl_xor(fp, o);
  if (j == 0) red[w] = fp;
  __syncthreads();          // also makes V diag writes visible
  const float tol = (red[0] + red[1] + red[2] + red[3]) * relTol + 1e-30f;

  for (int sweep = 0; sweep < MAXSWEEP; ++sweep) {
    for (int m = 1; m < 64; ++m) {
      const int b  = 31 - __clz(m);          // wave-uniform
      const int lm = (1 << b) - 1;

      // --- in-wave angles: every lane computes pair kk = 8w + (j&7) ---
      // (8-way same-address reads = LDS broadcast; safe: these rows are
      //  written only by THIS wave's row phase, which depends on cv/sv)
      const int kk = (w << 3) + (j & 7);
      const int pk = ((kk >> b) << (b + 1)) | (kk & lm);   // bit b clear
      const int qk = pk ^ m;
      float app = A[pk * LD + pk];
      float aqq = A[qk * LD + qk];
      float apq = A[pk * LD + qk];
      float cv = 1.0f, sv = 0.0f;
      if (fabsf(apq) > 1e-36f) {
        float th = (aqq - app) / (2.0f * apq);
        float t  = 1.0f / (fabsf(th) + sqrtf(th * th + 1.0f));
        if (th < 0.0f) t = -t;
        cv = 1.0f / sqrtf(t * t + 1.0f);
        sv = t * cv;
      }

      // --- row phase: 2 batches of 4 pairs (disjoint rows between batches) ---
      #pragma unroll
      for (int h2 = 0; h2 < 2; ++h2) {
        float c4[4], s4[4], ap[4], aq[4];
        int p4[4], q4[4];
        #pragma unroll
        for (int it = 0; it < 4; ++it) {
          const int k2 = (w << 3) + (h2 << 2) + it;
          p4[it] = ((k2 >> b) << (b + 1)) | (k2 & lm);
          q4[it] = p4[it] ^ m;
          c4[it] = __shfl(cv, (h2 << 2) + it);
          s4[it] = __shfl(sv, (h2 << 2) + it);
        }
        #pragma unroll
        for (int it = 0; it < 4; ++it) {
          ap[it] = A[p4[it] * LD + j];
          aq[it] = A[q4[it] * LD + j];
        }
        #pragma unroll
        for (int it = 0; it < 4; ++it) {
          A[p4[it] * LD + j] = c4[it] * ap[it] - s4[it] * aq[it];
          A[q4[it] * LD + j] = s4[it] * ap[it] + c4[it] * aq[it];
        }
      }
      __syncthreads();

      // --- col phase (+ V), same pairs, row = j, 2 batches of 4 ---
      float lo = 0.0f;
      #pragma unroll
      for (int h2 = 0; h2 < 2; ++h2) {
        float c4[4], s4[4], ap[4], aq[4];
        int p4[4], q4[4];
        #pragma unroll
        for (int it = 0; it < 4; ++it) {
          const int k2 = (w << 3) + (h2 << 2) + it;
          p4[it] = ((k2 >> b) << (b + 1)) | (k2 & lm);
          q4[it] = p4[it] ^ m;
          c4[it] = __shfl(cv, (h2 << 2) + it);
          s4[it] = __shfl(sv, (h2 << 2) + it);
        }
        #pragma unroll
        for (int it = 0; it < 4; ++it) {
          ap[it] = A[j * LD + p4[it]];
          aq[it] = A[j * LD + q4[it]];
        }
        #pragma unroll
        for (int it = 0; it < 4; ++it) {
          float np = c4[it] * ap[it] - s4[it] * aq[it];
          float nq = s4[it] * ap[it] + c4[it] * aq[it];
          A[j * LD + p4[it]] = np;
          A[j * LD + q4[it]] = nq;
          if (m == 63) {                     // free off^2 on the sweep's last round
            if (j != p4[it]) lo += np * np;
            if (j != q4[it]) lo += nq * nq;
          }
        }
        if (WITH_V) {
          #pragma unroll
          for (int it = 0; it < 4; ++it) {
            ap[it] = V[j * LD + p4[it]];
            aq[it] = V[j * LD + q4[it]];
          }
          #pragma unroll
          for (int it = 0; it < 4; ++it) {
            V[j * LD + p4[it]] = c4[it] * ap[it] - s4[it] * aq[it];
            V[j * LD + q4[it]] = s4[it] * ap[it] + c4[it] * aq[it];
          }
        }
      }
      if (m == 63) {
        #pragma unroll
        for (int o = 32; o > 0; o >>= 1) lo += __shfl_xor(lo, o);
        if (j == 0) red[w] = lo;
      }
      __syncthreads();
    }
    const float off2 = red[0] + red[1] + red[2] + red[3];
    if (off2 <= tol) break;     // uniform
  }
  __syncthreads();
}

// O = Lg @ S ; Lg global row-major 64 (wave-uniform scalar loads), S LDS (ld 65).
__device__ void gemm_gS(const float* __restrict__ Lg, const float* S, float* O)
{
  const int tid = threadIdx.x;
  const int j  = tid & 63;
  const int iw = __builtin_amdgcn_readfirstlane((tid >> 6) << 4);
  float acc[16];
  #pragma unroll
  for (int ii = 0; ii < 16; ++ii) acc[ii] = 0.0f;
  for (int kb = 0; kb < 64; kb += 4) {
    float sv0 = S[(kb + 0) * LD + j];
    float sv1 = S[(kb + 1) * LD + j];
    float sv2 = S[(kb + 2) * LD + j];
    float sv3 = S[(kb + 3) * LD + j];
    #pragma unroll
    for (int ii = 0; ii < 16; ++ii) {
      const float* lr = Lg + (iw + ii) * 64 + kb;   // wave-uniform -> s_load
      acc[ii] += lr[0] * sv0 + lr[1] * sv1 + lr[2] * sv2 + lr[3] * sv3;
    }
  }
  #pragma unroll
  for (int ii = 0; ii < 16; ++ii) O[(iw + ii) * LD + j] = acc[ii];
}

// O = S @ Rg with Rg SYMMETRIC global (rows, wave-uniform scalar):
// O[i][j] = sum_k S[i][k]*Rg[j*64+k]
__device__ void gemm_SgT(const float* S, const float* __restrict__ Rg, float* O)
{
  const int tid = threadIdx.x;
  const int i  = tid & 63;
  const int jw = __builtin_amdgcn_readfirstlane((tid >> 6) << 4);
  float acc[16];
  #pragma unroll
  for (int jj = 0; jj < 16; ++jj) acc[jj] = 0.0f;
  for (int kb = 0; kb < 64; kb += 4) {
    float s0 = S[i * LD + kb + 0];
    float s1 = S[i * LD + kb + 1];
    float s2 = S[i * LD + kb + 2];
    float s3 = S[i * LD + kb + 3];
    #pragma unroll
    for (int jj = 0; jj < 16; ++jj) {
      const float* rr = Rg + (jw + jj) * 64 + kb;   // wave-uniform -> s_load
      acc[jj] += s0 * rr[0] + s1 * rr[1] + s2 * rr[2] + s3 * rr[3];
    }
  }
  #pragma unroll
  for (int jj = 0; jj < 16; ++jj) O[i * LD + jw + jj] = acc[jj];
}

// O[i][j] = sum_k P[i][k] * w[k] * V[j][k]  (all LDS). O may alias V or P.
__device__ void gemm_ADT(const float* P, const float* w, const float* V, float* O)
{
  const int tid = threadIdx.x;
  const int i  = tid & 63;
  const int jw = __builtin_amdgcn_readfirstlane((tid >> 6) << 4);
  float acc[16];
  #pragma unroll
  for (int jj = 0; jj < 16; ++jj) acc[jj] = 0.0f;
  for (int k = 0; k < 64; ++k) {
    float pw = P[i * LD + k] * w[k];
    #pragma unroll
    for (int jj = 0; jj < 16; ++jj) acc[jj] += pw * V[(jw + jj) * LD + k];
  }
  __syncthreads();
  #pragma unroll
  for (int jj = 0; jj < 16; ++jj) O[i * LD + jw + jj] = acc[jj];
}

// --- prep: eigh(ref + eps I) -> rm = ref^{-1/2}, rp = ref^{1/2} into ws ---
__global__ __launch_bounds__(BLOCK, 4) void vae_prep(const float* __restrict__ ref,
                                                     float* __restrict__ rmrp)
{
  __shared__ __align__(16) float sA[NN * LD];
  __shared__ __align__(16) float sT[NN * LD];
  __shared__ float red[BLOCK];
  __shared__ float wb[64];
  const int tid = threadIdx.x;

  for (int idx = tid; idx < NN * NN; idx += BLOCK) {
    int i = idx >> 6, j = idx & 63;
    sA[i * LD + j] = ref[idx] + ((i == j) ? EPSF : 0.0f);
  }
  __syncthreads();
  jacobi64<true>(sA, sT, red, RELTOL_PREP);
  if (tid < 64) wb[tid] = sA[tid * LD + tid];
  __syncthreads();

  const int i  = tid & 63;
  const int jw = (tid >> 6) << 4;
  float am[16], aps[16];
  #pragma unroll
  for (int jj = 0; jj < 16; ++jj) { am[jj] = 0.0f; aps[jj] = 0.0f; }
  for (int k = 0; k < 64; ++k) {
    float vik = sT[i * LD + k];
    float wk  = wb[k];
    float rs  = 1.0f / sqrtf(wk);   // ref SPD: wk >= ~0.5
    float sq  = sqrtf(wk);
    float pr = vik * rs, pq = vik * sq;
    #pragma unroll
    for (int jj = 0; jj < 16; ++jj) {
      float vjk = sT[(jw + jj) * LD + k];
      am[jj]  += pr * vjk;
      aps[jj] += pq * vjk;
    }
  }
  #pragma unroll
  for (int jj = 0; jj < 16; ++jj) {
    rmrp[i * 64 + jw + jj]        = am[jj];
    rmrp[4096 + i * 64 + jw + jj] = aps[jj];
  }
}

// --- main: one block per batch item, fully fused ---
__global__ __launch_bounds__(BLOCK, 4) void vae_main(
    const float* __restrict__ x,   const float* __restrict__ ref,
    const float* __restrict__ rmrp,
    const float* __restrict__ w1,  const float* __restrict__ b1,
    const float* __restrict__ g1,  const float* __restrict__ bb1,
    const float* __restrict__ w2,  const float* __restrict__ b2,
    const float* __restrict__ g2,  const float* __restrict__ bb2,
    const float* __restrict__ muw, const float* __restrict__ mub,
    const float* __restrict__ lvw, const float* __restrict__ lvb,
    const float* __restrict__ dw1, const float* __restrict__ db1,
    const float* __restrict__ dg1, const float* __restrict__ dbb1,
    const float* __restrict__ dw2, const float* __restrict__ db2,
    const float* __restrict__ dg2, const float* __restrict__ dbb2,
    const float* __restrict__ dw3, const float* __restrict__ db3,
    float* __restrict__ out)
{
  __shared__ __align__(16) float sA[NN * LD];
  __shared__ __align__(16) float sT[NN * LD];   // also hosts svec (2080 <= 4160)
  __shared__ float red[BLOCK];
  __shared__ float h1s[128], h2s[64], zs[32], d1s[64], d2s[128];
  __shared__ float wb[64];
  __shared__ float shiftv;

  const int tid = threadIdx.x;
  const int b   = blockIdx.x;
  const float* rm = rmrp;
  const float* rp = rmrp + 4096;
  float* svec = sT;   // alias: sT is dead during the MLP phase

  // load x (shift for _ensure_spd(x) is provably 0: lambda_min(x) >= 0.5)
  for (int idx = tid; idx < 4096; idx += BLOCK)
    sA[(idx >> 6) * LD + (idx & 63)] = x[b * 4096 + idx];
  __syncthreads();

  gemm_gS(rm, sA, sT);            // T = rm @ x
  __syncthreads();
  gemm_SgT(sT, rm, sA);           // A = T @ rm = s
  __syncthreads();

  jacobi64<true>(sA, sT, red, RELTOL_MAIN);  // s = V w V^T (V in sT)
  if (tid < 64) wb[tid] = logf(fmaxf(sA[tid * LD + tid], 1e-12f));
  __syncthreads();

  gemm_gS(rm, sT, sA);            // A = rm @ V
  __syncthreads();
  gemm_ADT(sA, wb, sT, sT);       // T = (rm V) diag(log w) V^T  (alias-safe)
  __syncthreads();
  gemm_SgT(sT, rp, sA);           // A = tang = T @ rp
  __syncthreads();

  // vec = upper-triangle of tang (row-major triu order) -> svec (in sT)
  for (int idx = tid; idx < TRI; idx += BLOCK) {
    int i = (int)((129.0f - sqrtf(16641.0f - 8.0f * (float)idx)) * 0.5f);
    while (triOff(i + 1) <= idx) ++i;
    while (triOff(i) > idx) --i;
    int jj = i + (idx - triOff(i));
    svec[idx] = sA[i * LD + jj];
  }
  __syncthreads();

  // encoder L1: 2080 -> 128
  {
    int o = tid & 127, half = tid >> 7;
    const float4* wr = (const float4*)(w1 + o * 2080 + half * 1040);
    const float4* vv = (const float4*)(svec + half * 1040);
    float acc = 0.0f;
    for (int i4 = 0; i4 < 260; ++i4) {
      float4 a = wr[i4], v4 = vv[i4];
      acc += a.x * v4.x + a.y * v4.y + a.z * v4.z + a.w * v4.w;
    }
    red[tid] = acc;
    __syncthreads();
    if (tid < 128)
      h1s[tid] = bn_leaky(red[tid] + red[tid + 128] + b1[tid], g1[tid], bb1[tid]);
    __syncthreads();
  }
  // encoder L2: 128 -> 64
  {
    int o = tid & 63, half = tid >> 6;
    const float* wr = w2 + o * 128 + half * 32;
    const float* hh = h1s + half * 32;
    float acc = 0.0f;
    #pragma unroll 8
    for (int i = 0; i < 32; ++i) acc += wr[i] * hh[i];
    red[tid] = acc;
    __syncthreads();
    if (tid < 64)
      h2s[tid] = bn_leaky(red[tid] + red[tid + 64] + red[tid + 128] + red[tid + 192] + b2[tid],
                          g2[tid], bb2[tid]);
    __syncthreads();
  }
  // mu / logvar: 64 -> 32 each (z = mu)
  if (tid < 64) {
    int o = tid & 31;
    const float* wr = (tid < 32 ? muw : lvw) + o * 64;
    float acc = (tid < 32 ? mub : lvb)[o];
    for (int i = 0; i < 64; ++i) acc += wr[i] * h2s[i];
    if (tid < 32) { zs[o] = acc; out[MU_OFF + b * 32 + o] = acc; }
    else          { out[LV_OFF + b * 32 + o] = acc; }
  }
  __syncthreads();
  // decoder L1: 32 -> 64
  if (tid < 64) {
    const float* wr = dw1 + tid * 32;
    float acc = db1[tid];
    for (int i = 0; i < 32; ++i) acc += wr[i] * zs[i];
    d1s[tid] = bn_leaky(acc, dg1[tid], dbb1[tid]);
  }
  __syncthreads();
  // decoder L2: 64 -> 128
  if (tid < 128) {
    const float* wr = dw2 + tid * 64;
    float acc = db2[tid];
    for (int i = 0; i < 64; ++i) acc += wr[i] * d1s[i];
    d2s[tid] = bn_leaky(acc, dg2[tid], dbb2[tid]);
  }
  __syncthreads();
  // decoder L3: 128 -> 2080 (vdec into svec)
  for (int o = tid; o < TRI; o += BLOCK) {
    const float4* wr = (const float4*)(dw3 + o * 128);
    float acc = db3[o];
    #pragma unroll 8
    for (int k4 = 0; k4 < 32; ++k4) {
      float4 a = wr[k4];
      acc += a.x * d2s[k4 * 4] + a.y * d2s[k4 * 4 + 1] + a.z * d2s[k4 * 4 + 2] + a.w * d2s[k4 * 4 + 3];
    }
    svec[o] = acc;
  }
  __syncthreads();

  // mtil = symmetric(vdec) + eps I  -> sA
  for (int idx = tid; idx < 4096; idx += BLOCK) {
    int i = idx >> 6, jj = idx & 63;
    int lo = (i < jj) ? i : jj, hi = (i < jj) ? jj : i;
    sA[i * LD + jj] = svec[triOff(lo) + (hi - lo)] + ((i == jj) ? EPSF : 0.0f);
  }
  __syncthreads();

  // ===== exp(mtil) via scaling & squaring (replaces 2nd Jacobi eigh) =====
  {
    const int ti = tid >> 4;          // 0..15 (row tile)
    const int tj = tid & 15;          // 0..15 (col tile)
    const int r0 = ti << 2, c0 = tj << 2;

    // inf-norm (symmetric => bounds spectral norm)
    if (tid < 64) {
      float rs = 0.0f;
      for (int jj2 = 0; jj2 < 64; ++jj2) rs += fabsf(sA[tid * LD + jj2]);
      red[tid] = rs;
    }
    __syncthreads();
    if (tid < 32) red[tid] = fmaxf(red[tid], red[tid + 32]);
    __syncthreads();
    if (tid < 16) red[tid] = fmaxf(red[tid], red[tid + 16]);
    __syncthreads();
    if (tid < 8)  red[tid] = fmaxf(red[tid], red[tid + 8]);
    __syncthreads();
    if (tid < 4)  red[tid] = fmaxf(fmaxf(red[tid], red[tid + 4]),
                                   fmaxf(red[tid + 2] , red[(tid + 2) & 3]));
    __syncthreads();
    float R = fmaxf(fmaxf(red[0], red[1]), fmaxf(red[2], red[3]));

    int kpow = 0;
    float t = R;
    while (t > 0.25f && kpow < 24) { t *= 0.5f; ++kpow; }
    const float sc = ldexpf(1.0f, -kpow);

    // X = mtil * 2^-k (in place, sA)
    for (int idx = tid; idx < 4096; idx += BLOCK) {
      int i = idx >> 6, jj = idx & 63;
      sA[i * LD + jj] *= sc;
    }
    __syncthreads();

    // E = I + X + sum_{d=2..8} X^d/d!   (E in registers, powers ping in sT)
    float E[16];
    #pragma unroll
    for (int rr = 0; rr < 4; ++rr)
      #pragma unroll
      for (int c = 0; c < 4; ++c)
        E[rr * 4 + c] = ((r0 + rr) == (c0 + c) ? 1.0f : 0.0f) + sA[(r0 + rr) * LD + c0 + c];

    const float coef[7] = { 0.5f, 0.16666667f, 0.041666668f, 0.008333334f,
                            0.0013888889f, 1.9841270e-4f, 2.4801587e-5f };

    // d = 2: P = X*X  (reads sA only; sT dead after svec consumed)
    {
      float acc[16];
      #pragma unroll
      for (int u = 0; u < 16; ++u) acc[u] = 0.0f;
      for (int kk = 0; kk < 64; ++kk) {
        float a0 = sA[(r0 + 0) * LD + kk], a1 = sA[(r0 + 1) * LD + kk];
        float a2 = sA[(r0 + 2) * LD + kk], a3 = sA[(r0 + 3) * LD + kk];
        float b0 = sA[kk * LD + c0 + 0], b1v = sA[kk * LD + c0 + 1];
        float b2v = sA[kk * LD + c0 + 2], b3 = sA[kk * LD + c0 + 3];
        acc[0] += a0 * b0;  acc[1] += a0 * b1v;  acc[2] += a0 * b2v;  acc[3] += a0 * b3;
        acc[4] += a1 * b0;  acc[5] += a1 * b1v;  acc[6] += a1 * b2v;  acc[7] += a1 * b3;
        acc[8] += a2 * b0;  acc[9] += a2 * b1v;  acc[10] += a2 * b2v; acc[11] += a2 * b3;
        acc[12] += a3 * b0; acc[13] += a3 * b1v; acc[14] += a3 * b2v; acc[15] += a3 * b3;
      }
      __syncthreads();
      #pragma unroll
      for (int rr = 0; rr < 4; ++rr)
        #pragma unroll
        for (int c = 0; c < 4; ++c) {
          sT[(r0 + rr) * LD + c0 + c] = acc[rr * 4 + c];
          E[rr * 4 + c] += coef[0] * acc[rr * 4 + c];
        }
      __syncthreads();
    }
    // d = 3..8: P = P*X (in place via register staging)
    for (int d = 3; d <= 8; ++d) {
      float acc[16];
      #pragma unroll
      for (int u = 0; u < 16; ++u) acc[u] = 0.0f;
      for (int kk = 0; kk < 64; ++kk) {
        float a0 = sT[(r0 + 0) * LD + kk], a1 = sT[(r0 + 1) * LD + kk];
        float a2 = sT[(r0 + 2) * LD + kk], a3 = sT[(r0 + 3) * LD + kk];
        float b0 = sA[kk * LD + c0 + 0], b1v = sA[kk * LD + c0 + 1];
        float b2v = sA[kk * LD + c0 + 2], b3 = sA[kk * LD + c0 + 3];
        acc[0] += a0 * b0;  acc[1] += a0 * b1v;  acc[2] += a0 * b2v;  acc[3] += a0 * b3;
        acc[4] += a1 * b0;  acc[5] += a1 * b1v;  acc[6] += a1 * b2v;  acc[7] += a1 * b3;
        acc[8] += a2 * b0;  acc[9] += a2 * b1v;  acc[10] += a2 * b2v; acc[11] += a2 * b3;
        acc[12] += a3 * b0; acc[13] += a3 * b1v; acc[14] += a3 * b2v; acc[15] += a3 * b3;
      }
      __syncthreads();                       // all reads of sT done
      const float cd = coef[d - 2];
      #pragma unroll
      for (int rr = 0; rr < 4; ++rr)
        #pragma unroll
        for (int c = 0; c < 4; ++c) {
          sT[(r0 + rr) * LD + c0 + c] = acc[rr * 4 + c];
          E[rr * 4 + c] += cd * acc[rr * 4 + c];
        }
      __syncthreads();
    }
    // E -> sT
    #pragma unroll
    for (int rr = 0; rr < 4; ++rr)
      #pragma unroll
      for (int c = 0; c < 4; ++c)
        sT[(r0 + rr) * LD + c0 + c] = E[rr * 4 + c];
    __syncthreads();
    // square k times (in place via register staging)
    for (int itq = 0; itq < kpow; ++itq) {
      float acc[16];
      #pragma unroll
      for (int u = 0; u < 16; ++u) acc[u] = 0.0f;
      for (int kk = 0; kk < 64; ++kk) {
        float a0 = sT[(r0 + 0) * LD + kk], a1 = sT[(r0 + 1) * LD + kk];
        float a2 = sT[(r0 + 2) * LD + kk], a3 = sT[(r0 + 3) * LD + kk];
        float b0 = sT[kk * LD + c0 + 0], b1v = sT[kk * LD + c0 + 1];
        float b2v = sT[kk * LD + c0 + 2], b3 = sT[kk * LD + c0 + 3];
        acc[0] += a0 * b0;  acc[1] += a0 * b1v;  acc[2] += a0 * b2v;  acc[3] += a0 * b3;
        acc[4] += a1 * b0;  acc[5] += a1 * b1v;  acc[6] += a1 * b2v;  acc[7] += a1 * b3;
        acc[8] += a2 * b0;  acc[9] += a2 * b1v;  acc[10] += a2 * b2v; acc[11] += a2 * b3;
        acc[12] += a3 * b0; acc[13] += a3 * b1v; acc[14] += a3 * b2v; acc[15] += a3 * b3;
      }
      __syncthreads();
      #pragma unroll
      for (int rr = 0; rr < 4; ++rr)
        #pragma unroll
        for (int c = 0; c < 4; ++c)
          sT[(r0 + rr) * LD + c0 + c] = acc[rr * 4 + c];
      __syncthreads();
    }
  }
  // exp_a now in sT

  gemm_gS(ref, sT, sA);           // A = M2 = ref @ exp_a
  __syncthreads();

  // --- SPD shift: shift = max(EPS - lambda_min(sym_lower(M2)), 0)
  // Fast path: LDL^T PD-test of C = sym_lower(M2) - EPS*I (workspace sT).
  {
    for (int idx = tid; idx < 4096; idx += BLOCK) {
      int i = idx >> 6, jj = idx & 63;
      float v = (i >= jj) ? sA[i * LD + jj] : sA[jj * LD + i];
      sT[i * LD + jj] = v - ((i == jj) ? EPSF : 0.0f);
    }
    __syncthreads();

    bool pd = true;
    const int col = tid & 63;
    const int rw  = tid >> 6;
    for (int k = 0; k < 64; ++k) {
      float d = sT[k * LD + k];
      if (d <= 1e-30f) { pd = false; break; }
      if (col > k) {
        float ljk = sT[col * LD + k] / d;
        for (int i = k + 1 + rw; i < 64; i += 4) {
          float aik = sT[i * LD + k];
          sT[i * LD + col] -= aik * ljk;
        }
      }
      __syncthreads();
    }

    if (pd) {
      if (tid == 0) shiftv = 0.0f;
      __syncthreads();
    } else {
      __syncthreads();
      // Fallback: eigenvalues-only Jacobi on sym_lower(M2)
      for (int idx = tid; idx < 4096; idx += BLOCK) {
        int i = idx >> 6, jj = idx & 63;
        sT[i * LD + jj] = (i >= jj) ? sA[i * LD + jj] : sA[jj * LD + i];
      }
      __syncthreads();
      jacobi64<false>(sT, nullptr, red, RELTOL_VALS);
      if (tid == 0) {
        float mn = sT[0];
        for (int i = 1; i < 64; ++i) mn = fminf(mn, sT[i * LD + i]);
        shiftv = fmaxf(EPSF - mn, 0.0f);
      }
      __syncthreads();
    }
  }

  const float sh = shiftv;
  for (int idx = tid; idx < 4096; idx += BLOCK) {
    int i = idx >> 6, jj = idx & 63;
    out[b * 4096 + idx] = sA[i * LD + jj] + ((i == jj) ? sh : 0.0f);
  }
}

extern "C" void kernel_launch(void* const* d_in, const int* in_sizes, int n_in,
                              void* d_out, int out_size, void* d_ws, size_t ws_size,
                              hipStream_t stream) {
  (void)in_sizes; (void)n_in; (void)out_size; (void)ws_size;
  const float* x    = (const float*)d_in[0];
  const float* ref  = (const float*)d_in[1];
  const float* w1   = (const float*)d_in[2];
  const float* b1   = (const float*)d_in[3];
  const float* g1   = (const float*)d_in[4];
  const float* bb1  = (const float*)d_in[5];
  const float* w2   = (const float*)d_in[6];
  const float* b2   = (const float*)d_in[7];
  const float* g2   = (const float*)d_in[8];
  const float* bb2  = (const float*)d_in[9];
  const float* muw  = (const float*)d_in[10];
  const float* mub  = (const float*)d_in[11];
  const float* lvw  = (const float*)d_in[12];
  const float* lvb  = (const float*)d_in[13];
  const float* dw1  = (const float*)d_in[14];
  const float* db1  = (const float*)d_in[15];
  const float* dg1  = (const float*)d_in[16];
  const float* dbb1 = (const float*)d_in[17];
  const float* dw2  = (const float*)d_in[18];
  const float* db2  = (const float*)d_in[19];
  const float* dg2  = (const float*)d_in[20];
  const float* dbb2 = (const float*)d_in[21];
  const float* dw3  = (const float*)d_in[22];
  const float* db3  = (const float*)d_in[23];
  float* out = (float*)d_out;
  float* ws  = (float*)d_ws;   // rm (4096 floats) + rp (4096 floats)

  vae_prep<<<1, BLOCK, 0, stream>>>(ref, ws);
  vae_main<<<BATCH, BLOCK, 0, stream>>>(x, ref, ws,
      w1, b1, g1, bb1, w2, b2, g2, bb2, muw, mub, lvw, lvb,
      dw1, db1, dg1, dbb1, dw2, db2, dg2, dbb2, dw3, db3, out);
}